// Round 1
// baseline (613.918 us; speedup 1.0000x reference)
//
#include <hip/hip_runtime.h>

// Problem constants (match reference setup_inputs)
#define E_   8
#define H_   1024
#define F_   4096
#define DL_  256
#define TPE_ 1024
#define TT_  (E_ * TPE_)   // 8192 total tokens

typedef __attribute__((ext_vector_type(8))) short  short8;  // 8 bf16 (4 VGPRs)
typedef __attribute__((ext_vector_type(4))) float  f32x4;   // MFMA C/D frag

__device__ __forceinline__ unsigned short f2bf(float f) {
  // round-to-nearest-even fp32 -> bf16
  unsigned int u = __float_as_uint(f);
  u += 0x7fffu + ((u >> 16) & 1u);
  return (unsigned short)(u >> 16);
}

__device__ __forceinline__ void glds16(const void* g, void* l) {
  // async global->LDS, 16B per lane; LDS dest = wave-uniform base + lane*16
  __builtin_amdgcn_global_load_lds(
      (const __attribute__((address_space(1))) unsigned int*)g,
      (__attribute__((address_space(3))) unsigned int*)l, 16, 0, 0);
}

// ---------------------------------------------------------------------------
// fp32 -> bf16 convert (vectorized float4 -> ushort4)
__global__ void conv_bf16(const float* __restrict__ src,
                          unsigned short* __restrict__ dst, int n4) {
  int i = blockIdx.x * blockDim.x + threadIdx.x;
  int stride = gridDim.x * blockDim.x;
  for (; i < n4; i += stride) {
    float4 v = ((const float4*)src)[i];
    ushort4 o;
    o.x = f2bf(v.x); o.y = f2bf(v.y); o.z = f2bf(v.z); o.w = f2bf(v.w);
    ((ushort4*)dst)[i] = o;
  }
}

// w2 [E][F][H] fp32  ->  w2t [E][H][F] bf16  (LDS-tiled 64x64 transpose)
__global__ void transpose_conv(const float* __restrict__ src,
                               unsigned short* __restrict__ dst) {
  __shared__ unsigned short tile[64][65];  // +1 pad breaks bank aliasing
  const int e  = blockIdx.z;
  const int f0 = blockIdx.x * 64;
  const int h0 = blockIdx.y * 64;
  const float* s = src + (size_t)e * F_ * H_ + (size_t)f0 * H_ + h0;
#pragma unroll
  for (int it = 0; it < 16; ++it) {
    int lin = it * 256 + threadIdx.x;
    int r = lin >> 6, c = lin & 63;           // coalesced read along H
    tile[r][c] = f2bf(s[(size_t)r * H_ + c]);
  }
  __syncthreads();
  unsigned short* d = dst + (size_t)e * H_ * F_ + (size_t)h0 * F_ + f0;
#pragma unroll
  for (int it = 0; it < 16; ++it) {
    int lin = it * 256 + threadIdx.x;
    int a = lin >> 6, b = lin & 63;           // coalesced write along F
    d[(size_t)a * F_ + b] = tile[b][a];
  }
}

// ---------------------------------------------------------------------------
// Stage a 128x64 bf16 tile (row-major, leading dim `ld` elems) into linear LDS
// [128][64]. Each of 4 waves stages 32 rows via 4x global_load_lds (16B/lane).
__device__ __forceinline__ void stage_tile(const unsigned short* __restrict__ g,
                                           int ld, unsigned short* lds,
                                           int wid, int lane) {
#pragma unroll
  for (int q = 0; q < 4; ++q) {
    int row = wid * 32 + q * 8 + (lane >> 3);   // 8 lanes per 64-elem row
    int col = (lane & 7) << 3;
    glds16(g + (size_t)row * ld + col, lds + (size_t)(wid * 32 + q * 8) * 64);
  }
}

// One BK=64 compute step (2 x K=32 MFMA) accumulating into ACC[4][4]
#define KSTEP(ACC)                                                             \
  __syncthreads();                                                             \
  _Pragma("unroll")                                                            \
  for (int kk = 0; kk < 2; ++kk) {                                             \
    short8 af[4], bfr[4];                                                      \
    _Pragma("unroll")                                                          \
    for (int i = 0; i < 4; ++i)                                                \
      af[i] = *(const short8*)&As[(size_t)(wr * 64 + i * 16 + (lane & 15)) * 64 \
                                  + kk * 32 + (lane >> 4) * 8];                \
    _Pragma("unroll")                                                          \
    for (int j = 0; j < 4; ++j)                                                \
      bfr[j] = *(const short8*)&Bs[(size_t)(wc * 64 + j * 16 + (lane & 15)) * 64 \
                                   + kk * 32 + (lane >> 4) * 8];               \
    _Pragma("unroll")                                                          \
    for (int i = 0; i < 4; ++i)                                                \
      _Pragma("unroll")                                                        \
      for (int j = 0; j < 4; ++j)                                              \
        ACC[i][j] = __builtin_amdgcn_mfma_f32_16x16x32_bf16(af[i], bfr[j],     \
                                                            ACC[i][j], 0, 0, 0); \
  }                                                                            \
  __syncthreads();

// ---------------------------------------------------------------------------
// GEMM1: acc1 = acts@wup^T (K=256), acc2 = x@v1^T (K=1024); h = silu(acc1)*acc2
__global__ void __launch_bounds__(256, 2)
gemm1_kernel(const unsigned short* __restrict__ ab,    // [TT, DL]
             const unsigned short* __restrict__ xb,    // [TT, H]
             const unsigned short* __restrict__ wupb,  // [E][F][DL]
             const unsigned short* __restrict__ v1b,   // [E][F][H]
             unsigned short* __restrict__ hb) {        // [TT, F]
  __shared__ __align__(16) unsigned short As[128 * 64];
  __shared__ __align__(16) unsigned short Bs[128 * 64];
  const int bid = blockIdx.x;
  const int e  = bid >> 8;           // 256 blocks per expert (8 mt x 32 nt)
  const int rr = bid & 255;
  const int mt = rr >> 5;
  const int nt = rr & 31;
  const int m0 = e * TPE_ + mt * 128;   // global token row
  const int n0 = nt * 128;              // within F
  const int lane = threadIdx.x & 63;
  const int wid  = threadIdx.x >> 6;
  const int wr = wid >> 1, wc = wid & 1;

  f32x4 acc1[4][4], acc2[4][4];
#pragma unroll
  for (int i = 0; i < 4; ++i)
#pragma unroll
    for (int j = 0; j < 4; ++j) { acc1[i][j] = (f32x4)0.0f; acc2[i][j] = (f32x4)0.0f; }

  {  // phase 1: acts @ wup^T, K = DL = 256
    const unsigned short* Ab = ab + (size_t)m0 * DL_;
    const unsigned short* Bb = wupb + (size_t)e * F_ * DL_ + (size_t)n0 * DL_;
    for (int kt = 0; kt < DL_ / 64; ++kt) {
      stage_tile(Ab + kt * 64, DL_, As, wid, lane);
      stage_tile(Bb + kt * 64, DL_, Bs, wid, lane);
      KSTEP(acc1)
    }
  }
  {  // phase 2: x @ v1^T, K = H = 1024
    const unsigned short* Ab = xb + (size_t)m0 * H_;
    const unsigned short* Bb = v1b + (size_t)e * F_ * H_ + (size_t)n0 * H_;
    for (int kt = 0; kt < H_ / 64; ++kt) {
      stage_tile(Ab + kt * 64, H_, As, wid, lane);
      stage_tile(Bb + kt * 64, H_, Bs, wid, lane);
      KSTEP(acc2)
    }
  }
  // epilogue: h = silu(x1) * x2 -> bf16
#pragma unroll
  for (int i = 0; i < 4; ++i)
#pragma unroll
    for (int j = 0; j < 4; ++j)
#pragma unroll
      for (int r = 0; r < 4; ++r) {
        int row = m0 + wr * 64 + i * 16 + (lane >> 4) * 4 + r;
        int col = n0 + wc * 64 + j * 16 + (lane & 15);
        float g = acc1[i][j][r];
        float u = acc2[i][j][r];
        float s = g / (1.0f + __expf(-g));   // silu in fp32
        hb[(size_t)row * F_ + col] = f2bf(s * u);
      }
}

// GEMM2: out = h @ w2  (w2t is [E][H][F] so NT layout, K = F = 4096)
__global__ void __launch_bounds__(256, 2)
gemm2_kernel(const unsigned short* __restrict__ hb,    // [TT, F]
             const unsigned short* __restrict__ w2tb,  // [E][H][F]
             float* __restrict__ out) {                // [TT, H]
  __shared__ __align__(16) unsigned short As[128 * 64];
  __shared__ __align__(16) unsigned short Bs[128 * 64];
  const int bid = blockIdx.x;
  const int e  = bid >> 6;           // 64 blocks per expert (8 mt x 8 nt)
  const int rr = bid & 63;
  const int mt = rr >> 3;
  const int nt = rr & 7;
  const int m0 = e * TPE_ + mt * 128;
  const int n0 = nt * 128;           // within H
  const int lane = threadIdx.x & 63;
  const int wid  = threadIdx.x >> 6;
  const int wr = wid >> 1, wc = wid & 1;

  f32x4 acc[4][4];
#pragma unroll
  for (int i = 0; i < 4; ++i)
#pragma unroll
    for (int j = 0; j < 4; ++j) acc[i][j] = (f32x4)0.0f;

  const unsigned short* Ab = hb + (size_t)m0 * F_;
  const unsigned short* Bb = w2tb + (size_t)e * H_ * F_ + (size_t)n0 * F_;
  for (int kt = 0; kt < F_ / 64; ++kt) {
    stage_tile(Ab + kt * 64, F_, As, wid, lane);
    stage_tile(Bb + kt * 64, F_, Bs, wid, lane);
    KSTEP(acc)
  }
#pragma unroll
  for (int i = 0; i < 4; ++i)
#pragma unroll
    for (int j = 0; j < 4; ++j)
#pragma unroll
      for (int r = 0; r < 4; ++r) {
        int row = m0 + wr * 64 + i * 16 + (lane >> 4) * 4 + r;
        int col = n0 + wc * 64 + j * 16 + (lane & 15);
        out[(size_t)row * H_ + col] = acc[i][j][r];
      }
}

// ---------------------------------------------------------------------------
extern "C" void kernel_launch(void* const* d_in, const int* in_sizes, int n_in,
                              void* d_out, int out_size, void* d_ws, size_t ws_size,
                              hipStream_t stream) {
  const float* x    = (const float*)d_in[0];   // [TT, H]
  const float* acts = (const float*)d_in[1];   // [TT, DL]
  const float* wup  = (const float*)d_in[2];   // [E, F, DL]
  const float* v1   = (const float*)d_in[3];   // [E, F, H]
  const float* w2   = (const float*)d_in[4];   // [E, F, H]
  float* out = (float*)d_out;                  // [TT, H] fp32

  // ws layout (bf16 elements), total ~239 MB
  unsigned short* ws   = (unsigned short*)d_ws;
  unsigned short* hb   = ws;                                  // TT*F
  unsigned short* xb   = hb   + (size_t)TT_ * F_;             // TT*H
  unsigned short* abuf = xb   + (size_t)TT_ * H_;             // TT*DL
  unsigned short* wupb = abuf + (size_t)TT_ * DL_;            // E*F*DL
  unsigned short* v1b  = wupb + (size_t)E_ * F_ * DL_;        // E*F*H
  unsigned short* w2tb = v1b  + (size_t)E_ * F_ * H_;         // E*H*F

  conv_bf16<<<2048, 256, 0, stream>>>(x,    xb,   (TT_ * H_) / 4);
  conv_bf16<<<1024, 256, 0, stream>>>(acts, abuf, (TT_ * DL_) / 4);
  conv_bf16<<<2048, 256, 0, stream>>>(wup,  wupb, (E_ * F_ * DL_) / 4);
  conv_bf16<<<2048, 256, 0, stream>>>(v1,   v1b,  (E_ * F_ * H_) / 4);
  transpose_conv<<<dim3(F_ / 64, H_ / 64, E_), 256, 0, stream>>>(w2, w2tb);

  gemm1_kernel<<<E_ * (TPE_ / 128) * (F_ / 128), 256, 0, stream>>>(
      abuf, xb, wupb, v1b, hb);
  gemm2_kernel<<<E_ * (TPE_ / 128) * (H_ / 128), 256, 0, stream>>>(
      hb, w2tb, out);
}

// Round 5
// 596.521 us; speedup vs baseline: 1.0292x; 1.0292x over previous
//
#include <hip/hip_runtime.h>

// Problem constants (match reference setup_inputs)
#define E_   8
#define H_   1024
#define F_   4096
#define DL_  256
#define TPE_ 1024
#define TT_  (E_ * TPE_)   // 8192 total tokens

typedef __attribute__((ext_vector_type(8))) short  short8;  // 8 bf16 (4 VGPRs)
typedef __attribute__((ext_vector_type(4))) float  f32x4;   // MFMA C/D frag

__device__ __forceinline__ unsigned short f2bf(float f) {
  unsigned int u = __float_as_uint(f);
  u += 0x7fffu + ((u >> 16) & 1u);
  return (unsigned short)(u >> 16);
}
__device__ __forceinline__ float bf2f(unsigned short b) {
  return __uint_as_float(((unsigned int)b) << 16);
}

__device__ __forceinline__ void glds16(const void* g, void* l) {
  __builtin_amdgcn_global_load_lds(
      (const __attribute__((address_space(1))) unsigned int*)g,
      (__attribute__((address_space(3))) unsigned int*)l, 16, 0, 0);
}

// ---------------------------------------------------------------------------
// Fused prep: 4x fp32->bf16 convert segments + w2 [E][F][H] -> [E][H][F] bf16
#define NCONV_ 2048
__global__ void prep_kernel(const float* __restrict__ x,
                            const float* __restrict__ acts,
                            const float* __restrict__ wup,
                            const float* __restrict__ v1,
                            const float* __restrict__ w2,
                            unsigned short* __restrict__ xb,
                            unsigned short* __restrict__ ab,
                            unsigned short* __restrict__ wupb,
                            unsigned short* __restrict__ v1b,
                            unsigned short* __restrict__ w2tb) {
  __shared__ __align__(16) unsigned short tileT[64][72];  // [h][f], padded row
  if (blockIdx.x < NCONV_) {
    // grid-stride over concatenated float4 elements of {x, acts, wup, v1}
    const int c0 = (TT_ * H_) / 4;            // 2097152
    const int c1 = c0 + (TT_ * DL_) / 4;      // 2621440
    const int c2 = c1 + (E_ * F_ * DL_) / 4;  // 4718592
    const int c3 = c2 + (E_ * F_ * H_) / 4;   // 13107200
    int i = blockIdx.x * blockDim.x + threadIdx.x;
    const int stride = NCONV_ * 256;
    for (; i < c3; i += stride) {
      const float4* s;
      ushort4* d;
      int j;
      if (i < c0)      { s = (const float4*)x   + i;        d = (ushort4*)xb   + i; }
      else if (i < c1) { j = i - c0; s = (const float4*)acts + j; d = (ushort4*)ab   + j; }
      else if (i < c2) { j = i - c1; s = (const float4*)wup  + j; d = (ushort4*)wupb + j; }
      else             { j = i - c2; s = (const float4*)v1   + j; d = (ushort4*)v1b  + j; }
      float4 v = *s;
      ushort4 o;
      o.x = f2bf(v.x); o.y = f2bf(v.y); o.z = f2bf(v.z); o.w = f2bf(v.w);
      *d = o;
    }
  } else {
    // transpose+convert one 64(f) x 64(h) tile of w2
    const int t  = blockIdx.x - NCONV_;
    const int e  = t >> 10;          // 64*16 tiles per expert
    const int r  = t & 1023;
    const int fb = r >> 4;           // 0..63
    const int hbk = r & 15;          // 0..15
    const int tid = threadIdx.x;
    const float* s = w2 + (size_t)e * F_ * H_ + (size_t)fb * 64 * H_ + hbk * 64;
#pragma unroll
    for (int it = 0; it < 4; ++it) {
      int lin = it * 256 + tid;
      int f  = lin >> 4;             // 0..63
      int h4 = (lin & 15) << 2;      // 0..60 step 4
      float4 v = *(const float4*)(s + (size_t)f * H_ + h4);
      tileT[h4 + 0][f] = f2bf(v.x);
      tileT[h4 + 1][f] = f2bf(v.y);
      tileT[h4 + 2][f] = f2bf(v.z);
      tileT[h4 + 3][f] = f2bf(v.w);
    }
    __syncthreads();
    unsigned short* d = w2tb + (size_t)e * H_ * F_ + (size_t)(hbk * 64) * F_ + fb * 64;
#pragma unroll
    for (int it = 0; it < 2; ++it) {
      int lin = it * 256 + tid;
      int h  = lin >> 3;             // 0..63
      int f8 = (lin & 7) << 3;       // 0..56 step 8
      *(short8*)(d + (size_t)h * F_ + f8) = *(const short8*)&tileT[h][f8];
    }
  }
}

// ---------------------------------------------------------------------------
// Stage a 128x64 bf16 tile (row-major, leading dim `ld`) into linear LDS [128][64]
__device__ __forceinline__ void stage_tile(const unsigned short* __restrict__ g,
                                           int ld, unsigned short* lds,
                                           int wid, int lane) {
#pragma unroll
  for (int q = 0; q < 4; ++q) {
    int row = wid * 32 + q * 8 + (lane >> 3);
    int col = (lane & 7) << 3;
    glds16(g + (size_t)row * ld + col, lds + (size_t)(wid * 32 + q * 8) * 64);
  }
}

// One BK=64 compute step (2 x K=32 MFMA) accumulating into ACC[4][4]
#define KSTEP(ACC)                                                             \
  __syncthreads();                                                             \
  _Pragma("unroll")                                                            \
  for (int kk = 0; kk < 2; ++kk) {                                             \
    short8 af[4], bfr[4];                                                      \
    _Pragma("unroll")                                                          \
    for (int i = 0; i < 4; ++i)                                                \
      af[i] = *(const short8*)&As[(size_t)(wr * 64 + i * 16 + (lane & 15)) * 64 \
                                  + kk * 32 + (lane >> 4) * 8];                \
    _Pragma("unroll")                                                          \
    for (int j = 0; j < 4; ++j)                                                \
      bfr[j] = *(const short8*)&Bs[(size_t)(wc * 64 + j * 16 + (lane & 15)) * 64 \
                                   + kk * 32 + (lane >> 4) * 8];               \
    _Pragma("unroll")                                                          \
    for (int i = 0; i < 4; ++i)                                                \
      _Pragma("unroll")                                                        \
      for (int j = 0; j < 4; ++j)                                              \
        ACC[i][j] = __builtin_amdgcn_mfma_f32_16x16x32_bf16(af[i], bfr[j],     \
                                                            ACC[i][j], 0, 0, 0); \
  }                                                                            \
  __syncthreads();

#define TILE_PROLOGUE(NT_PER_E)                                                \
  __shared__ __align__(16) unsigned short As[128 * 64];                        \
  __shared__ __align__(16) unsigned short Bs[128 * 64];                        \
  const int bid = blockIdx.x;                                                  \
  const int e   = bid / (8 * NT_PER_E);                                        \
  const int rr  = bid % (8 * NT_PER_E);                                        \
  const int mt  = rr / NT_PER_E;                                               \
  const int nt  = rr % NT_PER_E;                                               \
  const int m0  = e * TPE_ + mt * 128;                                         \
  const int n0  = nt * 128;                                                    \
  const int lane = threadIdx.x & 63;                                           \
  const int wid  = threadIdx.x >> 6;                                           \
  const int wr = wid >> 1, wc = wid & 1;                                       \
  f32x4 acc[4][4];                                                             \
  _Pragma("unroll")                                                            \
  for (int i = 0; i < 4; ++i)                                                  \
    _Pragma("unroll")                                                          \
    for (int j = 0; j < 4; ++j) acc[i][j] = (f32x4)0.0f;

// gemm_x1: g = silu(acts @ wup^T), K = DL = 256. Writes bf16 g into hb.
__global__ void __launch_bounds__(256, 2)
gemm_x1_kernel(const unsigned short* __restrict__ ab,    // [TT, DL]
               const unsigned short* __restrict__ wupb,  // [E][F][DL]
               unsigned short* __restrict__ gb) {        // [TT, F]
  TILE_PROLOGUE(32)
  const unsigned short* Ab = ab + (size_t)m0 * DL_;
  const unsigned short* Bb = wupb + (size_t)e * F_ * DL_ + (size_t)n0 * DL_;
  for (int kt = 0; kt < DL_ / 64; ++kt) {
    stage_tile(Ab + kt * 64, DL_, As, wid, lane);
    stage_tile(Bb + kt * 64, DL_, Bs, wid, lane);
    KSTEP(acc)
  }
#pragma unroll
  for (int i = 0; i < 4; ++i)
#pragma unroll
    for (int j = 0; j < 4; ++j)
#pragma unroll
      for (int r = 0; r < 4; ++r) {
        int row = m0 + wr * 64 + i * 16 + (lane >> 4) * 4 + r;
        int col = n0 + wc * 64 + j * 16 + (lane & 15);
        float g = acc[i][j][r];
        float s = g / (1.0f + __expf(-g));
        gb[(size_t)row * F_ + col] = f2bf(s);
      }
}

// gemm_h: x2 = x @ v1^T (K=H=1024); h = g * x2 in-place in hb.
__global__ void __launch_bounds__(256, 2)
gemm_h_kernel(const unsigned short* __restrict__ xb,    // [TT, H]
              const unsigned short* __restrict__ v1b,   // [E][F][H]
              unsigned short* __restrict__ hb) {        // [TT, F] in: g, out: h
  TILE_PROLOGUE(32)
  const unsigned short* Ab = xb + (size_t)m0 * H_;
  const unsigned short* Bb = v1b + (size_t)e * F_ * H_ + (size_t)n0 * H_;
  for (int kt = 0; kt < H_ / 64; ++kt) {
    stage_tile(Ab + kt * 64, H_, As, wid, lane);
    stage_tile(Bb + kt * 64, H_, Bs, wid, lane);
    KSTEP(acc)
  }
#pragma unroll
  for (int i = 0; i < 4; ++i)
#pragma unroll
    for (int j = 0; j < 4; ++j)
#pragma unroll
      for (int r = 0; r < 4; ++r) {
        int row = m0 + wr * 64 + i * 16 + (lane >> 4) * 4 + r;
        int col = n0 + wc * 64 + j * 16 + (lane & 15);
        size_t idx = (size_t)row * F_ + col;
        float h = bf2f(hb[idx]) * acc[i][j][r];
        hb[idx] = f2bf(h);
      }
}

// gemm2: out = h @ w2t  (w2t is [E][H][F], NT layout, K = F = 4096)
__global__ void __launch_bounds__(256, 2)
gemm2_kernel(const unsigned short* __restrict__ hb,    // [TT, F]
             const unsigned short* __restrict__ w2tb,  // [E][H][F]
             float* __restrict__ out) {                // [TT, H]
  TILE_PROLOGUE(8)
  const unsigned short* Ab = hb + (size_t)m0 * F_;
  const unsigned short* Bb = w2tb + (size_t)e * H_ * F_ + (size_t)n0 * F_;
  for (int kt = 0; kt < F_ / 64; ++kt) {
    stage_tile(Ab + kt * 64, F_, As, wid, lane);
    stage_tile(Bb + kt * 64, F_, Bs, wid, lane);
    KSTEP(acc)
  }
#pragma unroll
  for (int i = 0; i < 4; ++i)
#pragma unroll
    for (int j = 0; j < 4; ++j)
#pragma unroll
      for (int r = 0; r < 4; ++r) {
        int row = m0 + wr * 64 + i * 16 + (lane >> 4) * 4 + r;
        int col = n0 + wc * 64 + j * 16 + (lane & 15);
        out[(size_t)row * H_ + col] = acc[i][j][r];
      }
}

// ---------------------------------------------------------------------------
extern "C" void kernel_launch(void* const* d_in, const int* in_sizes, int n_in,
                              void* d_out, int out_size, void* d_ws, size_t ws_size,
                              hipStream_t stream) {
  const float* x    = (const float*)d_in[0];   // [TT, H]
  const float* acts = (const float*)d_in[1];   // [TT, DL]
  const float* wup  = (const float*)d_in[2];   // [E, F, DL]
  const float* v1   = (const float*)d_in[3];   // [E, F, H]
  const float* w2   = (const float*)d_in[4];   // [E, F, H]
  float* out = (float*)d_out;                  // [TT, H] fp32

  // ws layout (bf16 elements), total ~239 MB
  unsigned short* ws   = (unsigned short*)d_ws;
  unsigned short* hb   = ws;                                  // TT*F  (g, then h)
  unsigned short* xb   = hb   + (size_t)TT_ * F_;             // TT*H
  unsigned short* abuf = xb   + (size_t)TT_ * H_;             // TT*DL
  unsigned short* wupb = abuf + (size_t)TT_ * DL_;            // E*F*DL
  unsigned short* v1b  = wupb + (size_t)E_ * F_ * DL_;        // E*F*H
  unsigned short* w2tb = v1b  + (size_t)E_ * F_ * H_;         // E*H*F

  prep_kernel<<<NCONV_ + (F_ / 64) * (H_ / 64) * E_, 256, 0, stream>>>(
      x, acts, wup, v1, w2, xb, abuf, wupb, v1b, w2tb);
  gemm_x1_kernel<<<E_ * 8 * 32, 256, 0, stream>>>(abuf, wupb, hb);
  gemm_h_kernel<<<E_ * 8 * 32, 256, 0, stream>>>(xb, v1b, hb);
  gemm2_kernel<<<E_ * 8 * 8, 256, 0, stream>>>(hb, w2tb, out);
}